// Round 9
// baseline (428.414 us; speedup 1.0000x reference)
//
#include <hip/hip_runtime.h>
#include <cstdint>
#include <cstddef>

#define D 128

typedef unsigned short ushort_t;
typedef unsigned int uint_t;
typedef __attribute__((ext_vector_type(8))) short bf16x8;
typedef __attribute__((ext_vector_type(4))) float f32x4;

static __device__ __forceinline__ unsigned short f2bf(float f) {
    unsigned int u = __float_as_uint(f);
    u = (u + 0x7FFFu + ((u >> 16) & 1u)) >> 16;  // RNE
    return (unsigned short)u;
}
static __device__ __forceinline__ float bf_lo(uint_t v) {
    return __uint_as_float(v << 16);
}
static __device__ __forceinline__ float bf_hi(uint_t v) {
    return __uint_as_float(v & 0xFFFF0000u);
}

static __device__ __forceinline__ void cast8(const float* __restrict__ s,
                                             ushort_t* __restrict__ d) {
    float4 a = *(const float4*)s;
    float4 b = *(const float4*)(s + 4);
    uint4 o;
    o.x = (uint_t)f2bf(a.x) | ((uint_t)f2bf(a.y) << 16);
    o.y = (uint_t)f2bf(a.z) | ((uint_t)f2bf(a.w) << 16);
    o.z = (uint_t)f2bf(b.x) | ((uint_t)f2bf(b.y) << 16);
    o.w = (uint_t)f2bf(b.z) | ((uint_t)f2bf(b.w) << 16);
    *(uint4*)d = o;
}

// ================= fused front-end: bkt_hist(1024 buckets) + casts =========

__global__ __launch_bounds__(256) void front_fused(
    const int* __restrict__ dst, int* __restrict__ bhist, int E, int EBH,
    const float* __restrict__ x, ushort_t* __restrict__ xb, long nx, int CX,
    const float* __restrict__ W1l, const float* __restrict__ W1r,
    const float* __restrict__ W2l, const float* __restrict__ W2r,
    ushort_t* __restrict__ W1lb, ushort_t* __restrict__ W1rb,
    ushort_t* __restrict__ W2lb, ushort_t* __restrict__ W2rb,
    int* __restrict__ row_ptr, int N) {
    __shared__ int lh[1024];
    int b = blockIdx.x, t = threadIdx.x;
    if (b == 0 && t == 0) row_ptr[N] = E;
    if (b < EBH) {
        lh[t] = 0; lh[t + 256] = 0; lh[t + 512] = 0; lh[t + 768] = 0;
        __syncthreads();
        int base = b * 4096;
#pragma unroll
        for (int i = 0; i < 16; ++i) {
            int e = base + i * 256 + t;
            if (e < E) atomicAdd(&lh[dst[e] >> 7], 1);
        }
        __syncthreads();
#pragma unroll
        for (int j = 0; j < 4; ++j) {
            int v = lh[t + j * 256];
            if (v) atomicAdd(&bhist[t + j * 256], v);
        }
    } else if (b < EBH + CX) {
        long i = ((long)(b - EBH) * 256 + t) * 8;
        if (i < nx) cast8(x + i, xb + i);
    } else {
        int bb = b - EBH - CX;  // 0..31; 8 blocks per weight array
        int arr = bb >> 3;
        long i = ((long)(bb & 7) * 256 + t) * 8;
        const float* s = (arr == 0) ? W1l : (arr == 1) ? W1r
                       : (arr == 2) ? W2l : W2r;
        ushort_t* d = (arr == 0) ? W1lb : (arr == 1) ? W1rb
                    : (arr == 2) ? W2lb : W2rb;
        cast8(s + i, d + i);
    }
}

// ================= CSR build: LDS-sorted scatter, 1024-edge chunks ==========
// pk = rank(10b)<<17 | bkt(10b)<<7 | dlocal(7b).  bcur zeroed by memset.
// Each block derives global bucket offsets from bhist via an in-block scan
// (no separate 1-block scan kernel).

__global__ __launch_bounds__(256) void bkt_scatter3(const int* __restrict__ src,
                                                    const int* __restrict__ dst,
                                                    const int* __restrict__ bhist,
                                                    int* __restrict__ bcur,
                                                    int* __restrict__ ebuf, int E) {
    __shared__ int lh[1024];
    __shared__ int lofs[1024];
    __shared__ int gbs[1024];
    __shared__ int tA[256];
    __shared__ int tB[256];
    __shared__ int sv[1024];
    __shared__ unsigned short sb[1024];
    int t = threadIdx.x;
    lh[t] = 0; lh[t + 256] = 0; lh[t + 512] = 0; lh[t + 768] = 0;
    __syncthreads();
    int base = blockIdx.x * 1024;
    unsigned pk[4];
#pragma unroll
    for (int i = 0; i < 4; ++i) {
        int e = base + i * 256 + t;
        unsigned p = 0xFFFFFFFFu;
        if (e < E) {
            int d = dst[e];
            int bkt = d >> 7;
            int r = atomicAdd(&lh[bkt], 1);
            p = ((unsigned)r << 17) | ((unsigned)bkt << 7) | (unsigned)(d & 127);
        }
        pk[i] = p;
    }
    __syncthreads();
    // dual exclusive scans over 1024 buckets (4/thread): local + global hist
    int la[4], ga[4];
#pragma unroll
    for (int j = 0; j < 4; ++j) {
        la[j] = lh[4 * t + j];
        ga[j] = bhist[4 * t + j];
    }
    int ls = la[0] + la[1] + la[2] + la[3];
    int gs = ga[0] + ga[1] + ga[2] + ga[3];
    tA[t] = ls;
    tB[t] = gs;
    __syncthreads();
    for (int off = 1; off < 256; off <<= 1) {
        int u1 = (t >= off) ? tA[t - off] : 0;
        int u2 = (t >= off) ? tB[t - off] : 0;
        __syncthreads();
        tA[t] += u1;
        tB[t] += u2;
        __syncthreads();
    }
    int lrun = tA[t] - ls;
    int grun = tB[t] - gs;
#pragma unroll
    for (int j = 0; j < 4; ++j) {
        lofs[4 * t + j] = lrun;
        gbs[4 * t + j] = grun;
        lrun += la[j];
        grun += ga[j];
    }
    __syncthreads();
#pragma unroll
    for (int j = 0; j < 4; ++j)
        if (la[j]) gbs[4 * t + j] += atomicAdd(&bcur[4 * t + j], la[j]);
    __syncthreads();
    // place edges bucket-sorted into LDS
#pragma unroll
    for (int i = 0; i < 4; ++i) {
        int e = base + i * 256 + t;
        if (e < E) {
            unsigned p = pk[i];
            int bkt = (p >> 7) & 1023;
            int r = (int)(p >> 17);
            int pos = lofs[bkt] + r;
            sv[pos] = src[e] | ((int)(p & 127) << 20);
            sb[pos] = (unsigned short)bkt;
        }
    }
    __syncthreads();
    // coalesced write-out (bucket runs)
    int cnt = min(E - base, 1024);
    for (int i = t; i < cnt; i += 256) {
        int b2 = sb[i];
        ebuf[gbs[b2] + (i - lofs[b2])] = sv[i];
    }
}

// build: one block per 128-node bucket (782 blocks)
__global__ __launch_bounds__(256) void bkt_build3(const int* __restrict__ ebuf,
                                                  const int* __restrict__ bhist,
                                                  int* __restrict__ row_ptr,
                                                  int* __restrict__ csr, int N) {
    __shared__ int scn[1024];
    __shared__ int tA[256];
    __shared__ int lcnt[128];
    __shared__ int lofs[128];
    __shared__ int lcur[128];
    int t = threadIdx.x;
    int b = blockIdx.x;
    // exclusive scan of bhist -> this bucket's edge range
    int ga[4];
#pragma unroll
    for (int j = 0; j < 4; ++j) ga[j] = bhist[4 * t + j];
    int gs = ga[0] + ga[1] + ga[2] + ga[3];
    tA[t] = gs;
    if (t < 128) lcnt[t] = 0;
    __syncthreads();
    for (int off = 1; off < 256; off <<= 1) {
        int u = (t >= off) ? tA[t - off] : 0;
        __syncthreads();
        tA[t] += u;
        __syncthreads();
    }
    int grun = tA[t] - gs;
#pragma unroll
    for (int j = 0; j < 4; ++j) {
        scn[4 * t + j] = grun;
        grun += ga[j];
    }
    __syncthreads();
    int ebeg = scn[b];
    int eend = ebeg + bhist[b];
    for (int e = ebeg + t; e < eend; e += 256)
        atomicAdd(&lcnt[((unsigned)ebuf[e]) >> 20], 1);
    __syncthreads();
    int v = 0;
    if (t < 128) {
        v = lcnt[t];
        lofs[t] = v;
    }
    __syncthreads();
    for (int off = 1; off < 128; off <<= 1) {
        int u = 0;
        if (t < 128 && t >= off) u = lofs[t - off];
        __syncthreads();
        if (t < 128) lofs[t] += u;
        __syncthreads();
    }
    if (t < 128) {
        int ex = lofs[t] - v;
        lofs[t] = ex;
        lcur[t] = 0;
        int node = (b << 7) + t;
        if (node < N) row_ptr[node] = ebeg + ex;
    }
    __syncthreads();
    for (int e = ebeg + t; e < eend; e += 256) {
        int u = ebuf[e];
        int d = ((unsigned)u) >> 20;
        int r = atomicAdd(&lcur[d], 1);
        csr[ebeg + lofs[d] + r] = u & 0xFFFFF;
    }
}

// ================= mean aggregation (R8-proven, byte-identical) =============

static __device__ __forceinline__ void acc8(uint4 v, float a[8]) {
    a[0] += bf_lo(v.x); a[1] += bf_hi(v.x);
    a[2] += bf_lo(v.y); a[3] += bf_hi(v.y);
    a[4] += bf_lo(v.z); a[5] += bf_hi(v.z);
    a[6] += bf_lo(v.w); a[7] += bf_hi(v.w);
}

static __device__ __forceinline__ uint4 grow(const ushort_t* __restrict__ xin,
                                             int s, int l16) {
    unsigned off = ((unsigned)s << 8) | ((unsigned)l16 << 4);  // bytes
    return *(const uint4*)((const char*)xin + off);
}

static __device__ __forceinline__ void agg_store(ushort_t* __restrict__ aggb,
                                                 int node, int l16,
                                                 const float a[8], int deg) {
    float inv = 1.0f / fmaxf((float)deg, 1.0f);
    uint4 o;
    o.x = (uint_t)f2bf(a[0] * inv) | ((uint_t)f2bf(a[1] * inv) << 16);
    o.y = (uint_t)f2bf(a[2] * inv) | ((uint_t)f2bf(a[3] * inv) << 16);
    o.z = (uint_t)f2bf(a[4] * inv) | ((uint_t)f2bf(a[5] * inv) << 16);
    o.w = (uint_t)f2bf(a[6] * inv) | ((uint_t)f2bf(a[7] * inv) << 16);
    unsigned off = ((unsigned)node << 8) | ((unsigned)l16 << 4);
    *(uint4*)((char*)aggb + off) = o;
}

__global__ __launch_bounds__(256) void agg_k2(const ushort_t* __restrict__ xin,
                                              const int* __restrict__ csr,
                                              const int* __restrict__ row_ptr,
                                              ushort_t* __restrict__ aggb, int N) {
    int wave = threadIdx.x >> 6;
    int lane = threadIdx.x & 63;
    int g = lane >> 4;    // row group 0..3
    int l16 = lane & 15;  // 16B segment within a 256B row
    int p = blockIdx.x * 8 + wave * 2;
    if (p >= N) return;
    int node0 = p;
    int node1 = min(p + 1, N - 1);  // tail duplicates node0 (benign rewrite)
    int b0 = row_ptr[node0];
    int deg0 = row_ptr[node0 + 1] - b0;
    int b1 = row_ptr[node1];
    int deg1 = row_ptr[node1 + 1] - b1;
    int d0 = min(deg0, 64), d1 = min(deg1, 64);
    int i0 = (deg0 > 0) ? csr[b0 + min(lane, deg0 - 1)] : 0;
    int i1 = (deg1 > 0) ? csr[b1 + min(lane, deg1 - 1)] : 0;
    int c0 = max(d0 - 1, 0), c1 = max(d1 - 1, 0);
    float a0[8] = {0.f, 0.f, 0.f, 0.f, 0.f, 0.f, 0.f, 0.f};
    float a1[8] = {0.f, 0.f, 0.f, 0.f, 0.f, 0.f, 0.f, 0.f};
    int mm = max(d0, d1);
    for (int e = 0; e < mm; e += 16) {
        bool do0 = (e < d0), do1 = (e < d1);  // wave-uniform
        uint4 v0[4], v1[4];
        if (do0) {
#pragma unroll
            for (int q = 0; q < 4; ++q) {
                int s = __shfl(i0, min(e + 4 * q + g, c0));
                v0[q] = grow(xin, s, l16);
            }
        }
        if (do1) {
#pragma unroll
            for (int q = 0; q < 4; ++q) {
                int s = __shfl(i1, min(e + 4 * q + g, c1));
                v1[q] = grow(xin, s, l16);
            }
        }
        if (do0) {
#pragma unroll
            for (int q = 0; q < 4; ++q)
                if (e + 4 * q + g < d0) acc8(v0[q], a0);
        }
        if (do1) {
#pragma unroll
            for (int q = 0; q < 4; ++q)
                if (e + 4 * q + g < d1) acc8(v1[q], a1);
        }
    }
    for (int e2 = 64; e2 < deg0; e2 += 4) {  // rare deg>64 fallback
        int s = csr[b0 + min(e2 + g, deg0 - 1)];
        uint4 v = grow(xin, s, l16);
        if (e2 + g < deg0) acc8(v, a0);
    }
    for (int e2 = 64; e2 < deg1; e2 += 4) {
        int s = csr[b1 + min(e2 + g, deg1 - 1)];
        uint4 v = grow(xin, s, l16);
        if (e2 + g < deg1) acc8(v, a1);
    }
#pragma unroll
    for (int i = 0; i < 8; ++i) {
        a0[i] += __shfl_xor(a0[i], 16);
        a1[i] += __shfl_xor(a1[i], 16);
        a0[i] += __shfl_xor(a0[i], 32);
        a1[i] += __shfl_xor(a1[i], 32);
    }
    if (g == 0) {
        agg_store(aggb, node0, l16, a0, deg0);
        agg_store(aggb, node1, l16, a1, deg1);
    }
}

// ================= MFMA GEMM: 64-row tiles (2x blocks, better occupancy) ====
// Same fragment/C-D layout as the proven 128-tile kernel; wave w owns rows
// [n0+16w, n0+16w+16), all 128 cols (8 col-tiles), K in 8 chunks of 32.

__global__ __launch_bounds__(256) void gemm_mfma64(const ushort_t* __restrict__ Aagg,
                                                   const ushort_t* __restrict__ Ax,
                                                   const ushort_t* __restrict__ Wl,
                                                   const ushort_t* __restrict__ Wr,
                                                   const float* __restrict__ bias,
                                                   ushort_t* __restrict__ out_bf,
                                                   float* __restrict__ out_f32,
                                                   int N, int relu_bf) {
    __shared__ ushort_t sA[64 * 32];   // 4 KB
    __shared__ ushort_t sW[128 * 32];  // 8 KB
    int tid = threadIdx.x;
    int wave = tid >> 6, lane = tid & 63;
    int quad = lane >> 4, l15 = lane & 15;
    int n0 = blockIdx.x * 64;
    int sr = tid >> 2;          // 0..63
    int sseg = (tid & 3) * 8;   // elem offset within 32-elem row

    f32x4 acc[8];
#pragma unroll
    for (int nt = 0; nt < 8; ++nt) acc[nt] = (f32x4){0.f, 0.f, 0.f, 0.f};

    int ga = min(n0 + sr, N - 1);

#pragma unroll
    for (int c = 0; c < 8; ++c) {
        const ushort_t* Ab = (c < 4) ? Aagg : Ax;
        const ushort_t* Wb = (c < 4) ? Wl : Wr;
        int koff = (c & 3) * 32 + sseg;
        bf16x8 va = *(const bf16x8*)(Ab + (size_t)ga * D + koff);
        bf16x8 vw0 = *(const bf16x8*)(Wb + (size_t)sr * D + koff);
        bf16x8 vw1 = *(const bf16x8*)(Wb + (size_t)(sr + 64) * D + koff);
        __syncthreads();  // previous chunk consumed
        *(bf16x8*)&sA[sr * 32 + sseg] = va;
        *(bf16x8*)&sW[sr * 32 + sseg] = vw0;
        *(bf16x8*)&sW[(sr + 64) * 32 + sseg] = vw1;
        __syncthreads();

        bf16x8 af = *(const bf16x8*)&sA[(wave * 16 + l15) * 32 + quad * 8];
        bf16x8 wf[8];
#pragma unroll
        for (int nt = 0; nt < 8; ++nt)
            wf[nt] = *(const bf16x8*)&sW[(nt * 16 + l15) * 32 + quad * 8];
#pragma unroll
        for (int nt = 0; nt < 8; ++nt)
            acc[nt] = __builtin_amdgcn_mfma_f32_16x16x32_bf16(af, wf[nt], acc[nt], 0, 0, 0);
    }

#pragma unroll
    for (int nt = 0; nt < 8; ++nt) {
        int col = nt * 16 + l15;
        float bv = bias[col];
#pragma unroll
        for (int reg = 0; reg < 4; ++reg) {
            int row = n0 + wave * 16 + quad * 4 + reg;
            if (row < N) {
                float v = acc[nt][reg] + bv;
                if (relu_bf) {
                    v = fmaxf(v, 0.f);
                    out_bf[(size_t)row * D + col] = f2bf(v);
                } else {
                    out_f32[(size_t)row * D + col] = v;
                }
            }
        }
    }
}

// ================= launch =================

extern "C" void kernel_launch(void* const* d_in, const int* in_sizes, int n_in,
                              void* d_out, int out_size, void* d_ws, size_t ws_size,
                              hipStream_t stream) {
    const float* x   = (const float*)d_in[0];
    const int*   ei  = (const int*)d_in[1];
    const float* W1l = (const float*)d_in[2];
    const float* b1  = (const float*)d_in[3];
    const float* W1r = (const float*)d_in[4];
    const float* W2l = (const float*)d_in[5];
    const float* b2  = (const float*)d_in[6];
    const float* W2r = (const float*)d_in[7];
    float* out = (float*)d_out;

    int N = in_sizes[0] / D;
    int E = in_sizes[1] / 2;
    const int* src = ei;
    const int* dst = ei + E;

    char* ws = (char*)d_ws;
    size_t off = 0;
    auto take = [&](size_t bytes) -> char* {
        char* p = ws + off;
        off += (bytes + 255) & ~(size_t)255;
        return p;
    };
    int*      row_ptr = (int*)take((size_t)(N + 1) * sizeof(int));
    int*      bhist   = (int*)take((size_t)2048 * sizeof(int));
    int*      bcur    = bhist + 1024;
    int*      ebuf    = (int*)take((size_t)E * sizeof(int));
    int*      csr     = (int*)take((size_t)E * sizeof(int));
    ushort_t* xb      = (ushort_t*)take((size_t)N * D * sizeof(ushort_t));
    ushort_t* hb      = (ushort_t*)take((size_t)N * D * sizeof(ushort_t));
    ushort_t* aggb    = (ushort_t*)take((size_t)N * D * sizeof(ushort_t));
    ushort_t* W1lb    = (ushort_t*)take((size_t)D * D * sizeof(ushort_t));
    ushort_t* W1rb    = (ushort_t*)take((size_t)D * D * sizeof(ushort_t));
    ushort_t* W2lb    = (ushort_t*)take((size_t)D * D * sizeof(ushort_t));
    ushort_t* W2rb    = (ushort_t*)take((size_t)D * D * sizeof(ushort_t));
    (void)ws_size;
    (void)n_in;
    (void)out_size;

    hipMemsetAsync(bhist, 0, 2048 * sizeof(int), stream);  // bhist + bcur

    int EBH = (E + 4095) / 4096;    // hist chunks
    int EBS = (E + 1023) / 1024;    // scatter chunks
    int NBB = (N + 127) / 128;      // 128-node buckets
    long nx = (long)N * D;
    int CX = (int)((nx / 8 + 255) / 256);

    front_fused<<<EBH + CX + 32, 256, 0, stream>>>(
        dst, bhist, E, EBH, x, xb, nx, CX,
        W1l, W1r, W2l, W2r, W1lb, W1rb, W2lb, W2rb, row_ptr, N);
    bkt_scatter3<<<EBS, 256, 0, stream>>>(src, dst, bhist, bcur, ebuf, E);
    bkt_build3<<<NBB, 256, 0, stream>>>(ebuf, bhist, row_ptr, csr, N);

    int ablocks = (N + 7) / 8;
    int gblocks = (N + 63) / 64;

    agg_k2<<<ablocks, 256, 0, stream>>>(xb, csr, row_ptr, aggb, N);
    gemm_mfma64<<<gblocks, 256, 0, stream>>>(aggb, xb, W1lb, W1rb, b1, hb, nullptr, N, 1);

    agg_k2<<<ablocks, 256, 0, stream>>>(hb, csr, row_ptr, aggb, N);
    gemm_mfma64<<<gblocks, 256, 0, stream>>>(aggb, hb, W2lb, W2rb, b2, nullptr, out, N, 0);
}

// Round 10
// 321.606 us; speedup vs baseline: 1.3321x; 1.3321x over previous
//
#include <hip/hip_runtime.h>
#include <cstdint>
#include <cstddef>

#define D 128

typedef unsigned short ushort_t;
typedef unsigned int uint_t;
typedef __attribute__((ext_vector_type(8))) short bf16x8;
typedef __attribute__((ext_vector_type(4))) float f32x4;

static __device__ __forceinline__ unsigned short f2bf(float f) {
    unsigned int u = __float_as_uint(f);
    u = (u + 0x7FFFu + ((u >> 16) & 1u)) >> 16;  // RNE
    return (unsigned short)u;
}
static __device__ __forceinline__ float bf_lo(uint_t v) {
    return __uint_as_float(v << 16);
}
static __device__ __forceinline__ float bf_hi(uint_t v) {
    return __uint_as_float(v & 0xFFFF0000u);
}

static __device__ __forceinline__ void cast8(const float* __restrict__ s,
                                             ushort_t* __restrict__ d) {
    float4 a = *(const float4*)s;
    float4 b = *(const float4*)(s + 4);
    uint4 o;
    o.x = (uint_t)f2bf(a.x) | ((uint_t)f2bf(a.y) << 16);
    o.y = (uint_t)f2bf(a.z) | ((uint_t)f2bf(a.w) << 16);
    o.z = (uint_t)f2bf(b.x) | ((uint_t)f2bf(b.y) << 16);
    o.w = (uint_t)f2bf(b.z) | ((uint_t)f2bf(b.w) << 16);
    *(uint4*)d = o;
}

// ================= fused front-end: per-block hist (NO atomics) + casts =====
// Hist blocks write their local 512-bucket histogram to blkhist[b][512]
// (coalesced). The 200K contended global atomicAdds of the old scheme
// (~50us of hot-line serialization, per R9's scatter3 evidence) are gone.

__global__ __launch_bounds__(256) void front_fused(
    const int* __restrict__ dst, int* __restrict__ blkhist, int E, int EB,
    const float* __restrict__ x, ushort_t* __restrict__ xb, long nx, int CX,
    const float* __restrict__ W1l, const float* __restrict__ W1r,
    const float* __restrict__ W2l, const float* __restrict__ W2r,
    ushort_t* __restrict__ W1lb, ushort_t* __restrict__ W1rb,
    ushort_t* __restrict__ W2lb, ushort_t* __restrict__ W2rb,
    int* __restrict__ row_ptr, int N) {
    __shared__ int lh[512];
    int b = blockIdx.x, t = threadIdx.x;
    if (b == 0 && t == 0) row_ptr[N] = E;
    if (b < EB) {
        lh[t] = 0;
        lh[t + 256] = 0;
        __syncthreads();
        int base = b * 4096;
#pragma unroll
        for (int i = 0; i < 16; ++i) {
            int e = base + i * 256 + t;
            if (e < E) atomicAdd(&lh[dst[e] >> 8], 1);  // LDS atomics only
        }
        __syncthreads();
        blkhist[(size_t)b * 512 + t] = lh[t];
        blkhist[(size_t)b * 512 + 256 + t] = lh[t + 256];
    } else if (b < EB + CX) {
        long i = ((long)(b - EB) * 256 + t) * 8;
        if (i < nx) cast8(x + i, xb + i);
    } else {
        int bb = b - EB - CX;  // 0..31; 8 blocks per weight array
        int arr = bb >> 3;
        long i = ((long)(bb & 7) * 256 + t) * 8;
        const float* s = (arr == 0) ? W1l : (arr == 1) ? W1r
                       : (arr == 2) ? W2l : W2r;
        ushort_t* d = (arr == 0) ? W1lb : (arr == 1) ? W1rb
                    : (arr == 2) ? W2lb : W2rb;
        cast8(s + i, d + i);
    }
}

// ================= column scan: deterministic radix offsets =================
// Block k: exclusive prefix of blkhist[b][k] over blocks b (in-place) and
// bucket total -> bhist[k]. Strided reads hit the same L2 lines across
// neighboring k-blocks (800KB total).

__global__ __launch_bounds__(256) void colscan(int* __restrict__ blkhist,
                                               int* __restrict__ bhist, int EB) {
    __shared__ int arr[512];
    __shared__ int tA[256];
    int k = blockIdx.x;  // bucket 0..511
    int t = threadIdx.x;
    arr[t] = (t < EB) ? blkhist[(size_t)t * 512 + k] : 0;
    arr[t + 256] = (t + 256 < EB) ? blkhist[(size_t)(t + 256) * 512 + k] : 0;
    __syncthreads();
    int a0 = arr[2 * t], a1 = arr[2 * t + 1];
    int ps = a0 + a1;
    tA[t] = ps;
    __syncthreads();
    for (int off = 1; off < 256; off <<= 1) {
        int u = (t >= off) ? tA[t - off] : 0;
        __syncthreads();
        tA[t] += u;
        __syncthreads();
    }
    int exb = tA[t] - ps;
    if (2 * t < EB) blkhist[(size_t)(2 * t) * 512 + k] = exb;
    if (2 * t + 1 < EB) blkhist[(size_t)(2 * t + 1) * 512 + k] = exb + a0;
    if (t == 255) bhist[k] = tA[255];
}

// ================= LDS-sorted scatter, deterministic bases (NO atomics) =====

__global__ __launch_bounds__(256) void bkt_scatter4(const int* __restrict__ src,
                                                    const int* __restrict__ dst,
                                                    const int* __restrict__ bhist,
                                                    const int* __restrict__ blkhist,
                                                    int* __restrict__ ebuf, int E) {
    __shared__ int lh[512];
    __shared__ int lofs[512];
    __shared__ int gbs[512];
    __shared__ int tA[256];
    __shared__ int tB[256];
    __shared__ int sv[4096];
    __shared__ unsigned short sb[4096];
    int t = threadIdx.x;
    int blk = blockIdx.x;
    lh[t] = 0;
    lh[t + 256] = 0;
    __syncthreads();
    int base = blk * 4096;
    unsigned pk[16];  // rank<<17 | bkt<<8 | dlocal
#pragma unroll
    for (int i = 0; i < 16; ++i) {
        int e = base + i * 256 + t;
        unsigned p = 0xFFFFFFFFu;
        if (e < E) {
            int d = dst[e];
            int bkt = d >> 8;
            int r = atomicAdd(&lh[bkt], 1);  // LDS only
            p = ((unsigned)r << 17) | ((unsigned)bkt << 8) | (unsigned)(d & 255);
        }
        pk[i] = p;
    }
    __syncthreads();
    // dual exclusive scans (2 buckets/thread): local hist + global bhist
    int a0 = lh[2 * t], a1 = lh[2 * t + 1];
    int g0 = bhist[2 * t], g1 = bhist[2 * t + 1];
    int ps = a0 + a1, gs = g0 + g1;
    tA[t] = ps;
    tB[t] = gs;
    __syncthreads();
    for (int off = 1; off < 256; off <<= 1) {
        int u1 = (t >= off) ? tA[t - off] : 0;
        int u2 = (t >= off) ? tB[t - off] : 0;
        __syncthreads();
        tA[t] += u1;
        tB[t] += u2;
        __syncthreads();
    }
    int lexb = tA[t] - ps;
    int gexb = tB[t] - gs;
    lofs[2 * t] = lexb;
    lofs[2 * t + 1] = lexb + a0;
    // deterministic write base: global bucket offset + this block's prefix
    gbs[2 * t] = gexb + blkhist[(size_t)blk * 512 + 2 * t];
    gbs[2 * t + 1] = gexb + g0 + blkhist[(size_t)blk * 512 + 2 * t + 1];
    __syncthreads();
    // place edges bucket-sorted into LDS
#pragma unroll
    for (int i = 0; i < 16; ++i) {
        int e = base + i * 256 + t;
        if (e < E) {
            unsigned p = pk[i];
            int bkt = (p >> 8) & 511;
            int r = (int)(p >> 17);
            int pos = lofs[bkt] + r;
            sv[pos] = src[e] | ((int)(p & 255) << 20);
            sb[pos] = (unsigned short)bkt;
        }
    }
    __syncthreads();
    // coalesced write-out (bucket runs)
    int cnt = min(E - base, 4096);
    for (int i = t; i < cnt; i += 256) {
        int b2 = sb[i];
        ebuf[gbs[b2] + (i - lofs[b2])] = sv[i];
    }
}

// ================= build per-node CSR (R8-proven) ===========================

__global__ __launch_bounds__(256) void bkt_build2(const int* __restrict__ ebuf,
                                                  const int* __restrict__ bhist,
                                                  int* __restrict__ row_ptr,
                                                  int* __restrict__ csr, int N) {
    __shared__ int scn[512];
    __shared__ int tA[256];
    __shared__ int lcnt[256];
    __shared__ int lofs[256];
    __shared__ int lcur[256];
    int t = threadIdx.x;
    int b = blockIdx.x;
    int base = b << 8;
    // exclusive scan of bhist to get this bucket's edge range
    int g0 = bhist[2 * t], g1 = bhist[2 * t + 1];
    int gs = g0 + g1;
    tA[t] = gs;
    __syncthreads();
    for (int off = 1; off < 256; off <<= 1) {
        int u = (t >= off) ? tA[t - off] : 0;
        __syncthreads();
        tA[t] += u;
        __syncthreads();
    }
    int gexb = tA[t] - gs;
    scn[2 * t] = gexb;
    scn[2 * t + 1] = gexb + g0;
    lcnt[t] = 0;
    __syncthreads();
    int ebeg = scn[b];
    int eend = ebeg + bhist[b];
    for (int e = ebeg + t; e < eend; e += 256)
        atomicAdd(&lcnt[((unsigned)ebuf[e]) >> 20], 1);
    __syncthreads();
    int v = lcnt[t];
    lofs[t] = v;
    __syncthreads();
    for (int off = 1; off < 256; off <<= 1) {
        int u = (t >= off) ? lofs[t - off] : 0;
        __syncthreads();
        lofs[t] += u;
        __syncthreads();
    }
    int ex = lofs[t] - v;
    __syncthreads();
    lofs[t] = ex;
    lcur[t] = 0;
    if (base + t < N) row_ptr[base + t] = ebeg + ex;
    __syncthreads();
    for (int e = ebeg + t; e < eend; e += 256) {
        int u = ebuf[e];
        int d = ((unsigned)u) >> 20;
        int r = atomicAdd(&lcur[d], 1);
        csr[ebeg + lofs[d] + r] = u & 0xFFFFF;
    }
}

// ================= mean aggregation (R8-proven, byte-identical) =============

static __device__ __forceinline__ void acc8(uint4 v, float a[8]) {
    a[0] += bf_lo(v.x); a[1] += bf_hi(v.x);
    a[2] += bf_lo(v.y); a[3] += bf_hi(v.y);
    a[4] += bf_lo(v.z); a[5] += bf_hi(v.z);
    a[6] += bf_lo(v.w); a[7] += bf_hi(v.w);
}

static __device__ __forceinline__ uint4 grow(const ushort_t* __restrict__ xin,
                                             int s, int l16) {
    unsigned off = ((unsigned)s << 8) | ((unsigned)l16 << 4);  // bytes
    return *(const uint4*)((const char*)xin + off);
}

static __device__ __forceinline__ void agg_store(ushort_t* __restrict__ aggb,
                                                 int node, int l16,
                                                 const float a[8], int deg) {
    float inv = 1.0f / fmaxf((float)deg, 1.0f);
    uint4 o;
    o.x = (uint_t)f2bf(a[0] * inv) | ((uint_t)f2bf(a[1] * inv) << 16);
    o.y = (uint_t)f2bf(a[2] * inv) | ((uint_t)f2bf(a[3] * inv) << 16);
    o.z = (uint_t)f2bf(a[4] * inv) | ((uint_t)f2bf(a[5] * inv) << 16);
    o.w = (uint_t)f2bf(a[6] * inv) | ((uint_t)f2bf(a[7] * inv) << 16);
    unsigned off = ((unsigned)node << 8) | ((unsigned)l16 << 4);
    *(uint4*)((char*)aggb + off) = o;
}

__global__ __launch_bounds__(256) void agg_k2(const ushort_t* __restrict__ xin,
                                              const int* __restrict__ csr,
                                              const int* __restrict__ row_ptr,
                                              ushort_t* __restrict__ aggb, int N) {
    int wave = threadIdx.x >> 6;
    int lane = threadIdx.x & 63;
    int g = lane >> 4;    // row group 0..3
    int l16 = lane & 15;  // 16B segment within a 256B row
    int p = blockIdx.x * 8 + wave * 2;
    if (p >= N) return;
    int node0 = p;
    int node1 = min(p + 1, N - 1);  // tail duplicates node0 (benign rewrite)
    int b0 = row_ptr[node0];
    int deg0 = row_ptr[node0 + 1] - b0;
    int b1 = row_ptr[node1];
    int deg1 = row_ptr[node1 + 1] - b1;
    int d0 = min(deg0, 64), d1 = min(deg1, 64);
    int i0 = (deg0 > 0) ? csr[b0 + min(lane, deg0 - 1)] : 0;
    int i1 = (deg1 > 0) ? csr[b1 + min(lane, deg1 - 1)] : 0;
    int c0 = max(d0 - 1, 0), c1 = max(d1 - 1, 0);
    float a0[8] = {0.f, 0.f, 0.f, 0.f, 0.f, 0.f, 0.f, 0.f};
    float a1[8] = {0.f, 0.f, 0.f, 0.f, 0.f, 0.f, 0.f, 0.f};
    int mm = max(d0, d1);
    for (int e = 0; e < mm; e += 16) {
        bool do0 = (e < d0), do1 = (e < d1);  // wave-uniform
        uint4 v0[4], v1[4];
        if (do0) {
#pragma unroll
            for (int q = 0; q < 4; ++q) {
                int s = __shfl(i0, min(e + 4 * q + g, c0));
                v0[q] = grow(xin, s, l16);
            }
        }
        if (do1) {
#pragma unroll
            for (int q = 0; q < 4; ++q) {
                int s = __shfl(i1, min(e + 4 * q + g, c1));
                v1[q] = grow(xin, s, l16);
            }
        }
        if (do0) {
#pragma unroll
            for (int q = 0; q < 4; ++q)
                if (e + 4 * q + g < d0) acc8(v0[q], a0);
        }
        if (do1) {
#pragma unroll
            for (int q = 0; q < 4; ++q)
                if (e + 4 * q + g < d1) acc8(v1[q], a1);
        }
    }
    for (int e2 = 64; e2 < deg0; e2 += 4) {  // rare deg>64 fallback
        int s = csr[b0 + min(e2 + g, deg0 - 1)];
        uint4 v = grow(xin, s, l16);
        if (e2 + g < deg0) acc8(v, a0);
    }
    for (int e2 = 64; e2 < deg1; e2 += 4) {
        int s = csr[b1 + min(e2 + g, deg1 - 1)];
        uint4 v = grow(xin, s, l16);
        if (e2 + g < deg1) acc8(v, a1);
    }
#pragma unroll
    for (int i = 0; i < 8; ++i) {
        a0[i] += __shfl_xor(a0[i], 16);
        a1[i] += __shfl_xor(a1[i], 16);
        a0[i] += __shfl_xor(a0[i], 32);
        a1[i] += __shfl_xor(a1[i], 32);
    }
    if (g == 0) {
        agg_store(aggb, node0, l16, a0, deg0);
        agg_store(aggb, node1, l16, a1, deg1);
    }
}

// ================= MFMA GEMM (R8-proven 128-tile, byte-identical) ===========

__global__ __launch_bounds__(256) void gemm_mfma(const ushort_t* __restrict__ Aagg,
                                                 const ushort_t* __restrict__ Ax,
                                                 const ushort_t* __restrict__ Wl,
                                                 const ushort_t* __restrict__ Wr,
                                                 const float* __restrict__ bias,
                                                 ushort_t* __restrict__ out_bf,
                                                 float* __restrict__ out_f32,
                                                 int N, int relu_bf) {
    __shared__ ushort_t sA[128 * 32];  // 8 KB
    __shared__ ushort_t sW[128 * 32];  // 8 KB
    int tid = threadIdx.x;
    int wave = tid >> 6, lane = tid & 63;
    int quad = lane >> 4, l15 = lane & 15;
    int wm = wave & 1, wc = wave >> 1;
    int n0 = blockIdx.x * 128;
    int sr = tid >> 2;
    int sseg = (tid & 3) * 8;

    f32x4 acc[4][4];
#pragma unroll
    for (int mt = 0; mt < 4; ++mt)
#pragma unroll
        for (int nt = 0; nt < 4; ++nt) acc[mt][nt] = (f32x4){0.f, 0.f, 0.f, 0.f};

    int ga0 = min(n0 + sr, N - 1);
    int ga1 = min(n0 + sr + 64, N - 1);

#pragma unroll
    for (int c = 0; c < 8; ++c) {
        const ushort_t* Ab = (c < 4) ? Aagg : Ax;
        const ushort_t* Wb = (c < 4) ? Wl : Wr;
        int koff = (c & 3) * 32 + sseg;
        bf16x8 va0 = *(const bf16x8*)(Ab + (size_t)ga0 * D + koff);
        bf16x8 va1 = *(const bf16x8*)(Ab + (size_t)ga1 * D + koff);
        bf16x8 vw0 = *(const bf16x8*)(Wb + (size_t)sr * D + koff);
        bf16x8 vw1 = *(const bf16x8*)(Wb + (size_t)(sr + 64) * D + koff);
        __syncthreads();
        *(bf16x8*)&sA[sr * 32 + sseg] = va0;
        *(bf16x8*)&sA[(sr + 64) * 32 + sseg] = va1;
        *(bf16x8*)&sW[sr * 32 + sseg] = vw0;
        *(bf16x8*)&sW[(sr + 64) * 32 + sseg] = vw1;
        __syncthreads();

        bf16x8 af[4], wf[4];
#pragma unroll
        for (int mt = 0; mt < 4; ++mt)
            af[mt] = *(const bf16x8*)&sA[(wm * 64 + mt * 16 + l15) * 32 + quad * 8];
#pragma unroll
        for (int nt = 0; nt < 4; ++nt)
            wf[nt] = *(const bf16x8*)&sW[(wc * 64 + nt * 16 + l15) * 32 + quad * 8];
#pragma unroll
        for (int mt = 0; mt < 4; ++mt)
#pragma unroll
            for (int nt = 0; nt < 4; ++nt)
                acc[mt][nt] = __builtin_amdgcn_mfma_f32_16x16x32_bf16(
                    af[mt], wf[nt], acc[mt][nt], 0, 0, 0);
    }

#pragma unroll
    for (int mt = 0; mt < 4; ++mt) {
#pragma unroll
        for (int nt = 0; nt < 4; ++nt) {
            int col = wc * 64 + nt * 16 + l15;
            float bv = bias[col];
#pragma unroll
            for (int reg = 0; reg < 4; ++reg) {
                int row = n0 + wm * 64 + mt * 16 + quad * 4 + reg;
                if (row < N) {
                    float v = acc[mt][nt][reg] + bv;
                    if (relu_bf) {
                        v = fmaxf(v, 0.f);
                        out_bf[(size_t)row * D + col] = f2bf(v);
                    } else {
                        out_f32[(size_t)row * D + col] = v;
                    }
                }
            }
        }
    }
}

// ================= launch =================

extern "C" void kernel_launch(void* const* d_in, const int* in_sizes, int n_in,
                              void* d_out, int out_size, void* d_ws, size_t ws_size,
                              hipStream_t stream) {
    const float* x   = (const float*)d_in[0];
    const int*   ei  = (const int*)d_in[1];
    const float* W1l = (const float*)d_in[2];
    const float* b1  = (const float*)d_in[3];
    const float* W1r = (const float*)d_in[4];
    const float* W2l = (const float*)d_in[5];
    const float* b2  = (const float*)d_in[6];
    const float* W2r = (const float*)d_in[7];
    float* out = (float*)d_out;

    int N = in_sizes[0] / D;
    int E = in_sizes[1] / 2;
    const int* src = ei;
    const int* dst = ei + E;

    int EB = (E + 4095) / 4096;
    int NB = (N + 255) / 256;
    long nx = (long)N * D;
    int CX = (int)((nx / 8 + 255) / 256);

    char* ws = (char*)d_ws;
    size_t off = 0;
    auto take = [&](size_t bytes) -> char* {
        char* p = ws + off;
        off += (bytes + 255) & ~(size_t)255;
        return p;
    };
    int*      row_ptr = (int*)take((size_t)(N + 1) * sizeof(int));
    int*      bhist   = (int*)take((size_t)512 * sizeof(int));
    int*      blkhist = (int*)take((size_t)EB * 512 * sizeof(int));
    int*      ebuf    = (int*)take((size_t)E * sizeof(int));
    int*      csr     = (int*)take((size_t)E * sizeof(int));
    ushort_t* xb      = (ushort_t*)take((size_t)N * D * sizeof(ushort_t));
    ushort_t* hb      = (ushort_t*)take((size_t)N * D * sizeof(ushort_t));
    ushort_t* aggb    = (ushort_t*)take((size_t)N * D * sizeof(ushort_t));
    ushort_t* W1lb    = (ushort_t*)take((size_t)D * D * sizeof(ushort_t));
    ushort_t* W1rb    = (ushort_t*)take((size_t)D * D * sizeof(ushort_t));
    ushort_t* W2lb    = (ushort_t*)take((size_t)D * D * sizeof(ushort_t));
    ushort_t* W2rb    = (ushort_t*)take((size_t)D * D * sizeof(ushort_t));
    (void)ws_size;
    (void)n_in;
    (void)out_size;

    front_fused<<<EB + CX + 32, 256, 0, stream>>>(
        dst, blkhist, E, EB, x, xb, nx, CX,
        W1l, W1r, W2l, W2r, W1lb, W1rb, W2lb, W2rb, row_ptr, N);
    colscan<<<512, 256, 0, stream>>>(blkhist, bhist, EB);
    bkt_scatter4<<<EB, 256, 0, stream>>>(src, dst, bhist, blkhist, ebuf, E);
    bkt_build2<<<NB, 256, 0, stream>>>(ebuf, bhist, row_ptr, csr, N);

    int ablocks = (N + 7) / 8;
    int gblocks = (N + 127) / 128;

    agg_k2<<<ablocks, 256, 0, stream>>>(xb, csr, row_ptr, aggb, N);
    gemm_mfma<<<gblocks, 256, 0, stream>>>(aggb, xb, W1lb, W1rb, b1, hb, nullptr, N, 1);

    agg_k2<<<ablocks, 256, 0, stream>>>(hb, csr, row_ptr, aggb, N);
    gemm_mfma<<<gblocks, 256, 0, stream>>>(aggb, hb, W2lb, W2rb, b2, nullptr, out, N, 0);
}